// Round 5
// baseline (34.566 us; speedup 1.0000x reference)
//
#include <hip/hip_runtime.h>
#include <math.h>

// B=4, 3 anchors, 85 ch. Layers g=10/20/40 -> P=300/1200/4800 pos/img.
// Global rows: l0 [0,1200), l1 [1200,6000), l2 [6000,25200). NROWS=25200.
//
// ws layout (all slots that are read are re-written every call):
//   flag    float[25200]    @ 0        (obj channel, full overwrite)
//   boxes   float4[25200]   @ 102400   (written for positive rows; gated by flag)
//   qbuf    float[25200*5]  @ 512000   (y channels 0..4 per row)
//   partials float[104]     @ 1016064
//   done    int             @ 1020160  (zeroed by k_scan each call)

#define NBLK 104
#define SCAP 512
#define NT4 535500   // float4 count of one side (25200*85/4)

__device__ __constant__ float c_anc[3][3][2] = {
  {{116.f, 90.f}, {156.f, 198.f}, {373.f, 326.f}},
  {{ 30.f, 61.f}, { 62.f,  45.f}, { 59.f, 119.f}},
  {{ 10.f, 13.f}, { 16.f,  30.f}, { 33.f,  23.f}}};

__device__ __forceinline__ float bce_f(float label, float logit) {
    return fmaxf(logit, 0.0f) - logit * label + log1pf(expf(-fabsf(logit)));
}

__global__ __launch_bounds__(256) void k_scan(
    const float* __restrict__ t0, const float* __restrict__ y0,
    const float* __restrict__ t1, const float* __restrict__ y1,
    const float* __restrict__ t2, const float* __restrict__ y2,
    float* __restrict__ flag, float4* __restrict__ boxes,
    float* __restrict__ qbuf, int* __restrict__ done)
{
    int gid = blockIdx.x * 256 + threadIdx.x;
    if (gid == 0) *done = 0;
    int stride = gridDim.x * 256;
    for (int i = gid; i < 2 * NT4; i += stride) {
        bool isY = i >= NT4;
        int f4 = isY ? i - NT4 : i;
        const float* src; int rowBase, fi;
        if (f4 < 25500)       { src = isY ? y0 : t0; fi = f4 * 4;              rowBase = 0;    }
        else if (f4 < 127500) { src = isY ? y1 : t1; fi = (f4 - 25500) * 4;    rowBase = 1200; }
        else                  { src = isY ? y2 : t2; fi = (f4 - 127500) * 4;   rowBase = 6000; }
        float4 v = *(const float4*)(src + fi);   // 16B-aligned: fi%4==0
        float xs[4] = {v.x, v.y, v.z, v.w};
        #pragma unroll
        for (int c = 0; c < 4; ++c) {
            int f = fi + c;
            int row = f / 85;              // magic-mul div
            int ch  = f - row * 85;
            float x = xs[c];
            int grow = rowBase + row;
            if (!isY) {
                if (ch == 4) {
                    flag[grow] = x;
                    if (x != 0.0f) {
                        const float* tp = src + (size_t)row * 85;
                        boxes[grow] = make_float4(tp[0], tp[1], tp[2], tp[3]);
                    }
                }
            } else {
                if (ch < 5) qbuf[grow * 5 + ch] = x;
            }
        }
    }
}

template<int P, int G>
__device__ __forceinline__ float layer_block(
    const float* __restrict__ t, const float* __restrict__ y,
    int img, int chunk, int rowBase, const float (*anc)[2],
    const float* __restrict__ flag, const float4* __restrict__ boxes,
    const float* __restrict__ qbuf,
    float4* sbox, int* scount)
{
    const int gbase = rowBase + img * P;           // global row of this image's pos 0
    const float* fimg = flag + gbase;

    // --- phase A: box list from compact flag array (coalesced float4 reads) ---
    if (threadIdx.x == 0) *scount = 0;
    __syncthreads();
    const float4* fimg4 = (const float4*)fimg;     // gbase%4==0 for all layers
    for (int k4 = threadIdx.x; k4 < P / 4; k4 += 256) {
        float4 fv = fimg4[k4];
        float fs[4] = {fv.x, fv.y, fv.z, fv.w};
        #pragma unroll
        for (int c = 0; c < 4; ++c) {
            if (fs[c] != 0.0f) {
                int off = atomicAdd(scount, 1);
                if (off < SCAP) sbox[off] = boxes[gbase + k4 * 4 + c];
            }
        }
    }
    __syncthreads();
    int cnt = *scount; if (cnt > SCAP) cnt = SCAP;
    int cntPad = (cnt + 7) & ~7;                   // zero-pad: iou(0-box)=0
    for (int k = cnt + threadIdx.x; k < cntPad; k += 256)
        sbox[k] = make_float4(0.f, 0.f, 0.f, 0.f);
    __syncthreads();

    // --- phase B: conf term, q-values from compact qbuf (20B/lane span) ---
    int pos = chunk * 256 + threadIdx.x;
    bool valid = pos < P;
    float acc = 0.0f, obj = 0.0f;
    if (valid) {
        const float* qp = qbuf + (size_t)(gbase + pos) * 5;
        float q0 = qp[0], q1 = qp[1], q2 = qp[2], q3 = qp[3], q4 = qp[4];
        obj = fimg[pos];
        int a = pos % 3, cell = pos / 3;
        int j = cell % G, i = cell / G;
        float aw = anc[a][0], ah = anc[a][1];
        float gi = (float)G;

        float px = (1.0f / (1.0f + expf(-q0)) + (float)j) / gi;
        float py = (1.0f / (1.0f + expf(-q1)) + (float)i) / gi;
        float pw = expf(q2) * aw * (1.0f / 320.0f);
        float ph = expf(q3) * ah * (1.0f / 320.0f);
        float phx = pw * 0.5f, phy = ph * 0.5f;
        float pminx = px - phx, pmaxx = px + phx;
        float pminy = py - phy, pmaxy = py + phy;
        float parea = pw * ph;

        float best = -INFINITY;
        for (int k0 = 0; k0 < cntPad; k0 += 8) {
            #pragma unroll
            for (int u = 0; u < 8; ++u) {
                float4 tb = sbox[k0 + u];
                float thx = tb.z * 0.5f, thy = tb.w * 0.5f;
                float wx = fminf(pmaxx, tb.x + thx) - fmaxf(pminx, tb.x - thx);
                float wy = fminf(pmaxy, tb.y + thy) - fmaxf(pminy, tb.y - thy);
                wx = fmaxf(wx, 0.0f);
                wy = fmaxf(wy, 0.0f);
                float inter = wx * wy;
                float iou = inter / (parea + tb.z * tb.w - inter);
                best = fmaxf(best, iou);
            }
        }
        float ignore = (best < 0.5f) ? 1.0f : 0.0f;
        float bce_c = fmaxf(q4, 0.0f) - q4 * obj + log1pf(expf(-fabsf(q4)));
        acc = (obj + (1.0f - obj) * ignore) * bce_c;   // gate==1 for positives
    }

    // --- phase C: positives, whole-wave per-channel (coalesced rows) ---
    const float* tslab = t + (size_t)img * P * 85;
    const float* yslab = y + (size_t)img * P * 85;
    unsigned long long m = __ballot(valid && obj != 0.0f);
    int lane = threadIdx.x & 63;
    int waveBase = chunk * 256 + (threadIdx.x & ~63);
    while (m) {
        int b = __ffsll(m) - 1; m &= m - 1;
        int ppos = waveBase + b;
        const float* tp = tslab + (size_t)ppos * 85;
        const float* yp = yslab + (size_t)ppos * 85;
        float tv1 = tp[lane], yv1 = yp[lane];           // ch 0..63
        bool has2 = lane < 21;
        float tv2 = 0.f, yv2 = 0.f;
        if (has2) { tv2 = tp[lane + 64]; yv2 = yp[lane + 64]; }  // ch 64..84

        float tw = __shfl(tv1, 2, 64);
        float th = __shfl(tv1, 3, 64);
        float bs = 2.0f - tw * th;
        int a = ppos % 3, cell = ppos / 3;
        int jj = cell % G, ii = cell / G;
        float aw = anc[a][0], ah = anc[a][1];

        float term;
        if (lane == 0)      term = bs * bce_f(tv1 * (float)G - (float)jj, yv1);
        else if (lane == 1) term = bs * bce_f(tv1 * (float)G - (float)ii, yv1);
        else if (lane == 2) { float d = logf(tv1 * 320.0f / aw) - yv1; term = bs * 0.5f * d * d; }
        else if (lane == 3) { float d = logf(tv1 * 320.0f / ah) - yv1; term = bs * 0.5f * d * d; }
        else if (lane == 4) term = 0.0f;               // conf for positives already in phase B
        else                term = bce_f(tv1, yv1);    // cls 5..63
        if (has2) term += bce_f(tv2, yv2);             // cls 64..84
        acc += term;
    }
    return acc;
}

__global__ __launch_bounds__(256) void k_main(
    const float* __restrict__ t0, const float* __restrict__ y0,
    const float* __restrict__ t1, const float* __restrict__ y1,
    const float* __restrict__ t2, const float* __restrict__ y2,
    const float* __restrict__ flag, const float4* __restrict__ boxes,
    const float* __restrict__ qbuf,
    float* __restrict__ partials, int* __restrict__ done,
    float* __restrict__ out)
{
    __shared__ float4 sbox[SCAP];
    __shared__ int scount;
    int blk = blockIdx.x;

    float acc;
    if (blk < 8)       acc = layer_block< 300, 10>(t0, y0, blk >> 1, blk & 1, 0, c_anc[0], flag, boxes, qbuf, sbox, &scount);
    else if (blk < 28) { int r = blk - 8;  acc = layer_block<1200, 20>(t1, y1, r / 5,  r % 5,  1200, c_anc[1], flag, boxes, qbuf, sbox, &scount); }
    else               { int r = blk - 28; acc = layer_block<4800, 40>(t2, y2, r / 19, r % 19, 6000, c_anc[2], flag, boxes, qbuf, sbox, &scount); }

    // block reduce
    float v = acc;
    #pragma unroll
    for (int o = 32; o > 0; o >>= 1) v += __shfl_down(v, o, 64);
    __shared__ float red[4];
    int lane = threadIdx.x & 63, w = threadIdx.x >> 6;
    if (lane == 0) red[w] = v;
    __syncthreads();

    // last-block-done finalize: wave 0 participates so partials load in parallel
    if (threadIdx.x < 64) {
        int old = 0;
        if (threadIdx.x == 0) {
            float p = ((red[0] + red[1]) + (red[2] + red[3])) * 0.25f;  // mean over B=4
            __hip_atomic_store(&partials[blk], p, __ATOMIC_RELAXED, __HIP_MEMORY_SCOPE_AGENT);
            old = __hip_atomic_fetch_add(done, 1, __ATOMIC_ACQ_REL, __HIP_MEMORY_SCOPE_AGENT);
        }
        old = __shfl(old, 0, 64);
        if (old == NBLK - 1) {
            float s = 0.0f;
            if (lane < NBLK - 64)
                s = __hip_atomic_load(&partials[lane + 64], __ATOMIC_RELAXED, __HIP_MEMORY_SCOPE_AGENT);
            s += __hip_atomic_load(&partials[lane], __ATOMIC_RELAXED, __HIP_MEMORY_SCOPE_AGENT);
            #pragma unroll
            for (int o = 32; o > 0; o >>= 1) s += __shfl_down(s, o, 64);
            if (lane == 0) out[0] = s;
        }
    }
}

extern "C" void kernel_launch(void* const* d_in, const int* in_sizes, int n_in,
                              void* d_out, int out_size, void* d_ws, size_t ws_size,
                              hipStream_t stream) {
    // setup_inputs dict order: t0, y0, t1, y1, t2, y2
    const float* t0 = (const float*)d_in[0];
    const float* y0 = (const float*)d_in[1];
    const float* t1 = (const float*)d_in[2];
    const float* y1 = (const float*)d_in[3];
    const float* t2 = (const float*)d_in[4];
    const float* y2 = (const float*)d_in[5];

    float*  flag     = (float*)d_ws;
    float4* boxes    = (float4*)((char*)d_ws + 102400);
    float*  qbuf     = (float*)((char*)d_ws + 512000);
    float*  partials = (float*)((char*)d_ws + 1016064);
    int*    done     = (int*)((char*)d_ws + 1020160);
    float*  out      = (float*)d_out;

    k_scan<<<2048, 256, 0, stream>>>(t0, y0, t1, y1, t2, y2, flag, boxes, qbuf, done);
    k_main<<<NBLK, 256, 0, stream>>>(t0, y0, t1, y1, t2, y2, flag, boxes, qbuf, partials, done, out);
}